// Round 2
// baseline (703.977 us; speedup 1.0000x reference)
//
#include <hip/hip_runtime.h>
#include <hip/hip_bf16.h>

#define NN   100000
#define EE   3200000
#define HH   32
#define BB   128
#define KMAX 96
#define LSTRIDE 97       // LDS row stride (96 is 0 mod 32 -> bank storm)
#define NBKT 256         // dst buckets
#define BSPAN 391        // ceil(NN/NBKT)
#define WSPAN 98         // csr-build window (4 windows/bucket)
#define EBLK 256         // edge-chunk blocks
#define CHUNK 12500      // EE / EBLK exactly

typedef float f32x4 __attribute__((ext_vector_type(4)));

// ws layout (bytes), non-overlapping (~60 MB)
static constexpr size_t Q_OFF      = 0;           // 2 half-tables: 2 x N*32B = 6.4 MB
static constexpr size_t AGG_OFF    = 6400000;     // 2 halves x N*16 f32 = 12.8 MB
static constexpr size_t H_OFF      = 19200000;    // N*32 f32 = 12.8 MB
static constexpr size_t EPACK_OFF  = 32000000;    // EE int = 12.8 MB
static constexpr size_t SRC_OFF    = 44800000;    // EE int dense csr
static constexpr size_t OFF_OFF    = 57600000;    // (N+1) int
static constexpr size_t HIST_OFF   = 58100000;    // EBLK*NBKT int = 256 KB
static constexpr size_t START_OFF  = 58400000;    // EBLK*NBKT int = 256 KB
static constexpr size_t BBASE_OFF  = 58700000;    // (NBKT+1) int
static constexpr size_t STATS_OFF  = 58710000;    // 4 layers x 64 f32
static constexpr size_t POOLED_OFF = 58711024;    // B*32 f32
static constexpr size_t PCNT_OFF   = 58727408;    // B f32
static constexpr size_t ZERO_OFF   = STATS_OFF;
static constexpr size_t ZERO_BYTES = 17920;

// ---- K1: per-block LDS histogram of dst buckets
__global__ __launch_bounds__(256) void hist_kernel(const int* __restrict__ ei,
                                                   int* __restrict__ hist) {
    __shared__ int lh[NBKT];
    int tid = threadIdx.x, blk = blockIdx.x;
    for (int i = tid; i < NBKT; i += 256) lh[i] = 0;
    __syncthreads();
    int e0 = blk * CHUNK;
    for (int e = e0 + tid; e < e0 + CHUNK; e += 256) {
        int d = ei[EE + e];
        atomicAdd(&lh[d / BSPAN], 1);
    }
    __syncthreads();
    for (int i = tid; i < NBKT; i += 256) hist[blk * NBKT + i] = lh[i];
}

// ---- K2 (fused totals+scan+starts): 1 block, thread t owns bucket t
__global__ __launch_bounds__(NBKT) void bucket_scan_kernel(const int* __restrict__ hist,
                                                           int* __restrict__ bbase,
                                                           int* __restrict__ start) {
    __shared__ int sm[NBKT];
    int t = threadIdx.x;
    int mine = 0;
    for (int blk = 0; blk < EBLK; blk++) mine += hist[blk * NBKT + t];
    sm[t] = mine;
    __syncthreads();
    for (int off = 1; off < NBKT; off <<= 1) {
        int v = (t >= off) ? sm[t - off] : 0;
        __syncthreads();
        sm[t] += v;
        __syncthreads();
    }
    int base = sm[t] - mine;   // exclusive
    bbase[t] = base;
    if (t == NBKT - 1) bbase[NBKT] = sm[t];
    int run = base;
    for (int blk = 0; blk < EBLK; blk++) {
        start[blk * NBKT + t] = run;
        run += hist[blk * NBKT + t];
    }
}

// ---- K3: scatter packed (src | dstoff<<17) into bucket-grouped array
__global__ __launch_bounds__(256) void scatter_kernel(const int* __restrict__ ei,
                                                      const int* __restrict__ start,
                                                      int* __restrict__ epack) {
    __shared__ int loff[NBKT];
    int tid = threadIdx.x, blk = blockIdx.x;
    for (int i = tid; i < NBKT; i += 256) loff[i] = start[blk * NBKT + i];
    __syncthreads();
    int e0 = blk * CHUNK;
    for (int e = e0 + tid; e < e0 + CHUNK; e += 256) {
        int s = ei[e];
        int d = ei[EE + e];
        int b = d / BSPAN;
        int slot = atomicAdd(&loff[b], 1);
        epack[slot] = s | ((d - b * BSPAN) << 17);
    }
}

// ---- K4: compact CSR build (r6 form + stride-97 LDS to kill bank conflicts)
__global__ __launch_bounds__(256) void csr_compact_kernel(const int* __restrict__ epack,
                                                          const int* __restrict__ bbase,
                                                          int* __restrict__ off,
                                                          int* __restrict__ srcs) {
    __shared__ int lcnt[WSPAN];
    __shared__ int lbase[WSPAN + 1];
    __shared__ int lcsr[WSPAN * LSTRIDE];   // 98*97*4 = 38024 B
    __shared__ int sh_before;
    int blk = blockIdx.x;
    int b = blk >> 2, w = blk & 3;
    int base = b * BSPAN;
    int span = NN - base;
    if (span <= 0) return;
    if (span > BSPAN) span = BSPAN;
    int wstart = w * WSPAN;
    if (wstart >= span) return;
    int wend = min(wstart + WSPAN, span);
    int wn = wend - wstart;
    int tid = threadIdx.x;
    if (tid == 0) sh_before = 0;
    for (int i = tid; i < wn; i += 256) lcnt[i] = 0;
    __syncthreads();
    int p0 = bbase[b], p1 = bbase[b + 1];
    int nbefore = 0;
    for (int i = p0 + tid; i < p1; i += 256) {
        int wd = epack[i];
        int ld = wd >> 17;
        if (ld < wstart) nbefore++;
        else if (ld < wend) {
            int slot = atomicAdd(&lcnt[ld - wstart], 1);
            if (slot < KMAX) lcsr[(ld - wstart) * LSTRIDE + slot] = wd & 0x1FFFF;
        }
    }
    atomicAdd(&sh_before, nbefore);
    __syncthreads();
    if (tid == 0) {
        int run = 0;
        for (int i = 0; i < wn; i++) { lbase[i] = run; run += min(lcnt[i], KMAX); }
        lbase[wn] = run;
    }
    __syncthreads();
    int w0 = p0 + sh_before;
    for (int i = tid; i < wn; i += 256) off[base + wstart + i] = w0 + lbase[i];
    if (base + wend == NN && tid == 0) off[NN] = w0 + lbase[wn];
    int m = lbase[wn];
    for (int j = tid; j < m; j += 256) {
        int lo = 0, hi = wn - 1;
        while (lo < hi) {
            int mid = (lo + hi + 1) >> 1;
            if (lbase[mid] <= j) lo = mid; else hi = mid - 1;
        }
        srcs[w0 + j] = lcsr[lo * LSTRIDE + (j - lbase[lo])];
    }
}

__device__ __forceinline__ unsigned bf16rn(float f) {
    unsigned b = __float_as_uint(f);
    return (b + 0x7fffu + ((b >> 16) & 1u)) >> 16;   // RNE
}

__device__ __forceinline__ void acc_row(float* a, uint4 v) {
    a[0] += __uint_as_float(v.x << 16);
    a[1] += __uint_as_float(v.x & 0xffff0000u);
    a[2] += __uint_as_float(v.y << 16);
    a[3] += __uint_as_float(v.y & 0xffff0000u);
    a[4] += __uint_as_float(v.z << 16);
    a[5] += __uint_as_float(v.z & 0xffff0000u);
    a[6] += __uint_as_float(v.w << 16);
    a[7] += __uint_as_float(v.w & 0xffff0000u);
}

// ---- projection q(bf16) = BN(h) @ w1, 4-way K-split: wave wv of each block owns
// K-rows [wv*FIN/4, (wv+1)*FIN/4) for the block's 64 nodes (w1 rows stay
// wave-uniform -> scalar loads); partials reduced via padded LDS. Grid = N/64.
// q is written as TWO half-tables [half][node][2 x uint4] of 3.2 MB each so the
// gather passes are L2-resident (4 MB/XCD).
template <int FIN>
__global__ __launch_bounds__(256) void proj_kernel(const float* __restrict__ hin,
                                                   const float* __restrict__ w1,
                                                   const float* __restrict__ stats_prev,
                                                   const float* __restrict__ gamma,
                                                   const float* __restrict__ beta,
                                                   uint4* __restrict__ q4) {
    constexpr int JC = FIN / 4;           // K rows per wave: 32 (FIN=128) / 8 (FIN=32)
    __shared__ float sa[32], sc[32];
    __shared__ float part[4 * 64 * 33];   // [wv][node][ch], +1 pad -> 33792 B
    int tid = threadIdx.x;
    if constexpr (FIN == 32) {
        if (tid < 32) {
            float mean = stats_prev[tid] * (1.0f / NN);
            float var  = fmaxf(stats_prev[32 + tid] * (1.0f / NN) - mean * mean, 0.f);
            float av = gamma[tid] * rsqrtf(var + 1e-5f);
            sa[tid] = av;
            sc[tid] = beta[tid] - mean * av;
        }
        __syncthreads();
    }
    int wv = __builtin_amdgcn_readfirstlane(tid >> 6);   // K-part, wave-uniform
    int ln = tid & 63;                                   // node within block
    int n = blockIdx.x * 64 + ln;
    float acc[32];
#pragma unroll
    for (int c = 0; c < 32; c++) acc[c] = 0.f;
    if (n < NN) {
        const float4* h4 = (const float4*)(hin + (size_t)n * FIN + wv * JC);
        float hv[JC];
#pragma unroll
        for (int k = 0; k < JC / 4; k++) {
            float4 v = h4[k];
            hv[4*k] = v.x; hv[4*k+1] = v.y; hv[4*k+2] = v.z; hv[4*k+3] = v.w;
        }
        if constexpr (FIN == 32) {
#pragma unroll
            for (int j = 0; j < JC; j++) hv[j] = fmaf(hv[j], sa[wv * JC + j], sc[wv * JC + j]);
        }
#pragma unroll 4
        for (int j = 0; j < JC; j++) {
            float hvj = hv[j];
            const float* wrow = w1 + (size_t)(wv * JC + j) * 32;  // wave-uniform -> s_load
#pragma unroll
            for (int c = 0; c < 32; c++) acc[c] = fmaf(hvj, wrow[c], acc[c]);
        }
    }
    float* my = part + (wv * 64 + ln) * 33;
#pragma unroll
    for (int c = 0; c < 32; c++) my[c] = acc[c];
    __syncthreads();
    // reduce 4 partials; thread t -> node t>>2, channels (t&3)*8..+8; write bf16 q
    int node = tid >> 2, p = tid & 3;
    int n2 = blockIdx.x * 64 + node;
    if (n2 >= NN) return;
    float r[8];
#pragma unroll
    for (int k = 0; k < 8; k++) {
        int c = p * 8 + k;
        r[k] = (part[(0 * 64 + node) * 33 + c] + part[(1 * 64 + node) * 33 + c])
             + (part[(2 * 64 + node) * 33 + c] + part[(3 * 64 + node) * 33 + c]);
    }
    uint4 u;
    u.x = bf16rn(r[0]) | (bf16rn(r[1]) << 16);
    u.y = bf16rn(r[2]) | (bf16rn(r[3]) << 16);
    u.z = bf16rn(r[4]) | (bf16rn(r[5]) << 16);
    u.w = bf16rn(r[6]) | (bf16rn(r[7]) << 16);
    // half h = p>>1 holds channels h*16..h*16+15; lane-slot p&1 is 16B within row
    int half = p >> 1;
    q4[(size_t)half * (2 * NN) + (size_t)n2 * 2 + (p & 1)] = u;
}

// ---- gather (half): agg_h[n] = q_h[n] + b1_h + sum q_h[src].
// q_h table is 3.2 MB -> L2-resident per XCD. 2 lanes/node x 16 B, 8-unrolled.
// srcs + agg writes nontemporal so streams don't evict the q table.
__global__ __launch_bounds__(256) void gather_half_kernel(const uint4* __restrict__ qh,
                                                          const int* __restrict__ srcs,
                                                          const int* __restrict__ off,
                                                          const float* __restrict__ b1h,
                                                          float* __restrict__ aggh) {
    int t = blockIdx.x * 256 + threadIdx.x;
    int n = t >> 1;
    if (n >= NN) return;
    int p = t & 1;
    float a[8];
#pragma unroll
    for (int k = 0; k < 8; k++) a[k] = b1h[p * 8 + k];
    acc_row(a, qh[(size_t)n * 2 + p]);   // self term
    int o0 = off[n];
    int d = off[n + 1] - o0;
    const int* lst = srcs + o0;
    int i = 0;
    for (; i + 8 <= d; i += 8) {
        int s0 = __builtin_nontemporal_load(lst + i);
        int s1 = __builtin_nontemporal_load(lst + i + 1);
        int s2 = __builtin_nontemporal_load(lst + i + 2);
        int s3 = __builtin_nontemporal_load(lst + i + 3);
        int s4 = __builtin_nontemporal_load(lst + i + 4);
        int s5 = __builtin_nontemporal_load(lst + i + 5);
        int s6 = __builtin_nontemporal_load(lst + i + 6);
        int s7 = __builtin_nontemporal_load(lst + i + 7);
        uint4 v0 = qh[(size_t)s0 * 2 + p];
        uint4 v1 = qh[(size_t)s1 * 2 + p];
        uint4 v2 = qh[(size_t)s2 * 2 + p];
        uint4 v3 = qh[(size_t)s3 * 2 + p];
        uint4 v4 = qh[(size_t)s4 * 2 + p];
        uint4 v5 = qh[(size_t)s5 * 2 + p];
        uint4 v6 = qh[(size_t)s6 * 2 + p];
        uint4 v7 = qh[(size_t)s7 * 2 + p];
        acc_row(a, v0); acc_row(a, v1); acc_row(a, v2); acc_row(a, v3);
        acc_row(a, v4); acc_row(a, v5); acc_row(a, v6); acc_row(a, v7);
    }
    for (; i < d; i++) {
        int s = __builtin_nontemporal_load(lst + i);
        acc_row(a, qh[(size_t)s * 2 + p]);
    }
    f32x4 f0, f1;
    f0.x = a[0]; f0.y = a[1]; f0.z = a[2]; f0.w = a[3];
    f1.x = a[4]; f1.y = a[5]; f1.z = a[6]; f1.w = a[7];
    f32x4* ar = (f32x4*)(aggh + (size_t)n * 16 + p * 8);
    __builtin_nontemporal_store(f0, ar);
    __builtin_nontemporal_store(f1, ar + 1);
}

// ---- MLP tail: h = relu(relu(agg)@w2 + b2); accumulate raw BN stats (layer slot).
// agg now lives as two dense [N][16] halves.
__global__ __launch_bounds__(256) void mlp_kernel(const float* __restrict__ aggA,
                                                  const float* __restrict__ aggB,
                                                  const float* __restrict__ w2,
                                                  const float* __restrict__ b2,
                                                  float* __restrict__ r,
                                                  float* __restrict__ stats) {
    __shared__ float tile[256 * 33];
    __shared__ float ps[8 * 32];
    __shared__ float pq[8 * 32];
    int tid = threadIdx.x;
    int n = blockIdx.x * 256 + tid;
    float rc[32];
    if (n < NN) {
        float u[32];
        const float4* a4 = (const float4*)(aggA + (size_t)n * 16);
        const float4* b4 = (const float4*)(aggB + (size_t)n * 16);
#pragma unroll
        for (int k = 0; k < 4; k++) {
            float4 v = a4[k];
            u[4*k]   = fmaxf(v.x, 0.f);
            u[4*k+1] = fmaxf(v.y, 0.f);
            u[4*k+2] = fmaxf(v.z, 0.f);
            u[4*k+3] = fmaxf(v.w, 0.f);
        }
#pragma unroll
        for (int k = 0; k < 4; k++) {
            float4 v = b4[k];
            u[16+4*k]   = fmaxf(v.x, 0.f);
            u[16+4*k+1] = fmaxf(v.y, 0.f);
            u[16+4*k+2] = fmaxf(v.z, 0.f);
            u[16+4*k+3] = fmaxf(v.w, 0.f);
        }
#pragma unroll
        for (int c = 0; c < 32; c++) rc[c] = b2[c];
#pragma unroll 4
        for (int j = 0; j < 32; j++) {
            float uj = u[j];
            const float* wrow = w2 + (size_t)j * 32;
#pragma unroll
            for (int c = 0; c < 32; c++) rc[c] = fmaf(uj, wrow[c], rc[c]);
        }
#pragma unroll
        for (int c = 0; c < 32; c++) rc[c] = fmaxf(rc[c], 0.f);
        float4* rr = (float4*)(r + (size_t)n * 32);
#pragma unroll
        for (int k = 0; k < 8; k++) {
            float4 v; v.x = rc[4*k]; v.y = rc[4*k+1]; v.z = rc[4*k+2]; v.w = rc[4*k+3];
            rr[k] = v;
        }
    } else {
#pragma unroll
        for (int c = 0; c < 32; c++) rc[c] = 0.f;
    }
#pragma unroll
    for (int c = 0; c < 32; c++) tile[tid * 33 + c] = rc[c];
    __syncthreads();
    {
        int c = tid & 31, rb = tid >> 5;
        float s = 0.f, sq = 0.f;
        for (int it = 0; it < 32; it++) {
            float v = tile[(rb * 32 + it) * 33 + c];
            s += v; sq += v * v;
        }
        ps[rb * 32 + c] = s; pq[rb * 32 + c] = sq;
    }
    __syncthreads();
    if (tid < 32) {
        float s = 0.f, sq = 0.f;
#pragma unroll
        for (int rb = 0; rb < 8; rb++) { s += ps[rb * 32 + tid]; sq += pq[rb * 32 + tid]; }
        atomicAdd(&stats[tid], s);
        atomicAdd(&stats[32 + tid], sq);
    }
}

// ---- pooling: segment sums of raw h3 (sorted batch -> run-length flush)
#define PR 16
__global__ __launch_bounds__(256) void pool_kernel(const float* __restrict__ h,
                                                   const int* __restrict__ batch,
                                                   float* __restrict__ pooled,
                                                   float* __restrict__ pcnt) {
    int t = blockIdx.x * 256 + threadIdx.x;
    int c = t & 31;
    int g = t >> 5;
    int r0 = g * PR;
    if (r0 >= NN) return;
    int r1 = min(r0 + PR, NN);
    int cur = batch[r0];
    float acc = 0.f, cn = 0.f;
    for (int rr = r0; rr < r1; rr++) {
        int b = batch[rr];
        if (b != cur) {
            atomicAdd(&pooled[cur * 32 + c], acc);
            if (c == 0) atomicAdd(&pcnt[cur], cn);
            acc = 0.f; cn = 0.f; cur = b;
        }
        acc += h[(size_t)rr * 32 + c];
        cn += 1.f;
    }
    atomicAdd(&pooled[cur * 32 + c], acc);
    if (c == 0) atomicAdd(&pcnt[cur], cn);
}

// ---- head: BN3 (from raw stats3) on pooled means, fc1+relu, fc2, log_softmax
__global__ __launch_bounds__(128) void head_kernel(const float* __restrict__ pooled,
                                                   const float* __restrict__ pcnt,
                                                   const float* __restrict__ stats3,
                                                   const float* __restrict__ g3,
                                                   const float* __restrict__ be3,
                                                   const float* __restrict__ fc1w,
                                                   const float* __restrict__ fc1b,
                                                   const float* __restrict__ fc2w,
                                                   const float* __restrict__ fc2b,
                                                   float* __restrict__ out) {
    __shared__ float sa[32], sc[32];
    int g = threadIdx.x;
    if (g < 32) {
        float mean = stats3[g] * (1.0f / NN);
        float var  = fmaxf(stats3[32 + g] * (1.0f / NN) - mean * mean, 0.f);
        float av = g3[g] * rsqrtf(var + 1e-5f);
        sa[g] = av;
        sc[g] = be3[g] - mean * av;
    }
    __syncthreads();
    if (g >= BB) return;
    float inv = 1.f / fmaxf(pcnt[g], 1.f);
    float xv[32];
#pragma unroll
    for (int c = 0; c < 32; c++) xv[c] = fmaf(sa[c], pooled[g * 32 + c] * inv, sc[c]);
    float u[32];
#pragma unroll 4
    for (int k = 0; k < 32; k++) {
        float s = fc1b[k];
#pragma unroll
        for (int c = 0; c < 32; c++) s = fmaf(xv[c], fc1w[c * 32 + k], s);
        u[k] = fmaxf(s, 0.f);
    }
    float l[8];
#pragma unroll
    for (int o = 0; o < 8; o++) {
        float s = fc2b[o];
#pragma unroll
        for (int k = 0; k < 32; k++) s = fmaf(u[k], fc2w[k * 8 + o], s);
        l[o] = s;
    }
    float m = l[0];
#pragma unroll
    for (int o = 1; o < 8; o++) m = fmaxf(m, l[o]);
    float se = 0.f;
#pragma unroll
    for (int o = 0; o < 8; o++) se += expf(l[o] - m);
    float lse = logf(se) + m;
#pragma unroll
    for (int o = 0; o < 8; o++) out[g * 8 + o] = l[o] - lse;
}

extern "C" void kernel_launch(void* const* d_in, const int* in_sizes, int n_in,
                              void* d_out, int out_size, void* d_ws, size_t ws_size,
                              hipStream_t stream) {
    const float* x    = (const float*)d_in[0];
    const int*   ei   = (const int*)d_in[1];
    const int*   batch= (const int*)d_in[2];
    const float* w1_0 = (const float*)d_in[3];
    const float* b1_0 = (const float*)d_in[4];
    const float* w2_0 = (const float*)d_in[5];
    const float* b2_0 = (const float*)d_in[6];
    const float* g_0  = (const float*)d_in[7];
    const float* be_0 = (const float*)d_in[8];
    const float* w1s  = (const float*)d_in[9];
    const float* b1s  = (const float*)d_in[10];
    const float* w2s  = (const float*)d_in[11];
    const float* b2s  = (const float*)d_in[12];
    const float* gs   = (const float*)d_in[13];
    const float* bes  = (const float*)d_in[14];
    const float* fc1w = (const float*)d_in[15];
    const float* fc1b = (const float*)d_in[16];
    const float* fc2w = (const float*)d_in[17];
    const float* fc2b = (const float*)d_in[18];
    float* out = (float*)d_out;

    char* ws = (char*)d_ws;
    uint4*    q4     = (uint4*)(ws + Q_OFF);        // [2][N][2] uint4
    float*    agg    = (float*)(ws + AGG_OFF);      // [2][N][16] f32
    float*    h      = (float*)(ws + H_OFF);
    int*      epack  = (int*)(ws + EPACK_OFF);
    int*      srcs   = (int*)(ws + SRC_OFF);
    int*      off    = (int*)(ws + OFF_OFF);
    int*      hist   = (int*)(ws + HIST_OFF);
    int*      start  = (int*)(ws + START_OFF);
    int*      bbase  = (int*)(ws + BBASE_OFF);
    float*    stats  = (float*)(ws + STATS_OFF);   // 4 slots x 64
    float*    pooled = (float*)(ws + POOLED_OFF);
    float*    pcnt   = (float*)(ws + PCNT_OFF);

    const uint4* qA = q4;
    const uint4* qB = q4 + (size_t)2 * NN;
    float* aggA = agg;
    float* aggB = agg + (size_t)NN * 16;

    (void)hipMemsetAsync(ws + ZERO_OFF, 0, ZERO_BYTES, stream);

    // CSR build chain
    hist_kernel<<<EBLK, 256, 0, stream>>>(ei, hist);
    bucket_scan_kernel<<<1, NBKT, 0, stream>>>(hist, bbase, start);
    scatter_kernel<<<EBLK, 256, 0, stream>>>(ei, start, epack);
    csr_compact_kernel<<<NBKT * 4, 256, 0, stream>>>(epack, bbase, off, srcs);

    const int pblk = (NN + 63) / 64;
    const int nblk = (NN + 255) / 256;
    const int ghblk = (NN * 2 + 255) / 256;

    // layer 0 (F_IN=128, no input BN)
    proj_kernel<128><<<pblk, 256, 0, stream>>>(x, w1_0, nullptr, nullptr, nullptr, q4);
    gather_half_kernel<<<ghblk, 256, 0, stream>>>(qA, srcs, off, b1_0, aggA);
    gather_half_kernel<<<ghblk, 256, 0, stream>>>(qB, srcs, off, b1_0 + 16, aggB);
    mlp_kernel<<<nblk, 256, 0, stream>>>(aggA, aggB, w2_0, b2_0, h, stats);

    // layers 1..3, prev BN computed in proj from raw stats slot
    for (int i = 0; i < 3; i++) {
        const float* st_prev = stats + i * 64;
        proj_kernel<32><<<pblk, 256, 0, stream>>>(h, w1s + i * 1024, st_prev,
                                                  gs + i * 32, bes + i * 32, q4);
        gather_half_kernel<<<ghblk, 256, 0, stream>>>(qA, srcs, off, b1s + i * 32, aggA);
        gather_half_kernel<<<ghblk, 256, 0, stream>>>(qB, srcs, off, b1s + i * 32 + 16, aggB);
        mlp_kernel<<<nblk, 256, 0, stream>>>(aggA, aggB, w2s + i * 1024, b2s + i * 32, h,
                                             stats + (i + 1) * 64);
    }

    int pthreads = ((NN + PR - 1) / PR) * 32;
    pool_kernel<<<(pthreads + 255) / 256, 256, 0, stream>>>(h, batch, pooled, pcnt);
    head_kernel<<<1, 128, 0, stream>>>(pooled, pcnt, stats + 3 * 64, gs + 2 * 32,
                                       bes + 2 * 32, fc1w, fc1b, fc2w, fc2b, out);
}

// Round 3
// 609.525 us; speedup vs baseline: 1.1550x; 1.1550x over previous
//
#include <hip/hip_runtime.h>
#include <hip/hip_bf16.h>

#define NN   100000
#define NHALF 50000
#define EE   3200000
#define HH   32
#define BB   128
#define KMAX 96
#define LSTRIDE 97       // LDS row stride; lo slots 0..95 up, hi slots 96..1 down
#define NBKT 256         // dst buckets
#define BSPAN 391        // ceil(NN/NBKT)
#define WSPAN 98         // csr-build window (4 windows/bucket)
#define EBLK 256         // edge-chunk blocks
#define CHUNK 12500      // EE / EBLK exactly

typedef float f32x4 __attribute__((ext_vector_type(4)));

// ws layout (bytes), non-overlapping (~60 MB)
static constexpr size_t Q_OFF      = 0;           // N*64B bf16 rows = 6.4 MB
static constexpr size_t AGG_OFF    = 6400000;     // N*32 f32 = 12.8 MB
static constexpr size_t H_OFF      = 19200000;    // N*32 f32 = 12.8 MB
static constexpr size_t EPACK_OFF  = 32000000;    // EE int = 12.8 MB
static constexpr size_t SRC_OFF    = 44800000;    // EE int dense csr
static constexpr size_t OFF_OFF    = 57600000;    // (N+1) int
static constexpr size_t HIST_OFF   = 58100000;    // EBLK*NBKT int = 256 KB
static constexpr size_t START_OFF  = 58400000;    // EBLK*NBKT int = 256 KB
static constexpr size_t BBASE_OFF  = 58700000;    // (NBKT+1) int
static constexpr size_t STATS_OFF  = 58710000;    // 4 layers x 64 f32
static constexpr size_t POOLED_OFF = 58711024;    // B*32 f32
static constexpr size_t PCNT_OFF   = 58727408;    // B f32
static constexpr size_t SP_OFF     = 58800000;    // N int (lo/hi split points)
static constexpr size_t ZERO_OFF   = STATS_OFF;
static constexpr size_t ZERO_BYTES = 17920;

// ---- K1: per-block LDS histogram of dst buckets
__global__ __launch_bounds__(256) void hist_kernel(const int* __restrict__ ei,
                                                   int* __restrict__ hist) {
    __shared__ int lh[NBKT];
    int tid = threadIdx.x, blk = blockIdx.x;
    for (int i = tid; i < NBKT; i += 256) lh[i] = 0;
    __syncthreads();
    int e0 = blk * CHUNK;
    for (int e = e0 + tid; e < e0 + CHUNK; e += 256) {
        int d = ei[EE + e];
        atomicAdd(&lh[d / BSPAN], 1);
    }
    __syncthreads();
    for (int i = tid; i < NBKT; i += 256) hist[blk * NBKT + i] = lh[i];
}

// ---- K2 (fused totals+scan+starts): 1 block, thread t owns bucket t
__global__ __launch_bounds__(NBKT) void bucket_scan_kernel(const int* __restrict__ hist,
                                                           int* __restrict__ bbase,
                                                           int* __restrict__ start) {
    __shared__ int sm[NBKT];
    int t = threadIdx.x;
    int mine = 0;
    for (int blk = 0; blk < EBLK; blk++) mine += hist[blk * NBKT + t];
    sm[t] = mine;
    __syncthreads();
    for (int off = 1; off < NBKT; off <<= 1) {
        int v = (t >= off) ? sm[t - off] : 0;
        __syncthreads();
        sm[t] += v;
        __syncthreads();
    }
    int base = sm[t] - mine;   // exclusive
    bbase[t] = base;
    if (t == NBKT - 1) bbase[NBKT] = sm[t];
    int run = base;
    for (int blk = 0; blk < EBLK; blk++) {
        start[blk * NBKT + t] = run;
        run += hist[blk * NBKT + t];
    }
}

// ---- K3: scatter packed (src | dstoff<<17) into bucket-grouped array
__global__ __launch_bounds__(256) void scatter_kernel(const int* __restrict__ ei,
                                                      const int* __restrict__ start,
                                                      int* __restrict__ epack) {
    __shared__ int loff[NBKT];
    int tid = threadIdx.x, blk = blockIdx.x;
    for (int i = tid; i < NBKT; i += 256) loff[i] = start[blk * NBKT + i];
    __syncthreads();
    int e0 = blk * CHUNK;
    for (int e = e0 + tid; e < e0 + CHUNK; e += 256) {
        int s = ei[e];
        int d = ei[EE + e];
        int b = d / BSPAN;
        int slot = atomicAdd(&loff[b], 1);
        epack[slot] = s | ((d - b * BSPAN) << 17);
    }
}

// ---- K4: compact CSR build with src-half partition (lo: src<NHALF first, then hi).
// sp[n] = absolute index of the lo/hi split within srcs[off[n]..off[n+1]).
__global__ __launch_bounds__(256) void csr_compact_kernel(const int* __restrict__ epack,
                                                          const int* __restrict__ bbase,
                                                          int* __restrict__ off,
                                                          int* __restrict__ sp,
                                                          int* __restrict__ srcs) {
    __shared__ int lcnt_lo[WSPAN];
    __shared__ int lcnt_hi[WSPAN];
    __shared__ int lbase[WSPAN + 1];
    __shared__ int lcsr[WSPAN * LSTRIDE];   // 98*97*4 = 38024 B
    __shared__ int sh_before;
    int blk = blockIdx.x;
    int b = blk >> 2, w = blk & 3;
    int base = b * BSPAN;
    int span = NN - base;
    if (span <= 0) return;
    if (span > BSPAN) span = BSPAN;
    int wstart = w * WSPAN;
    if (wstart >= span) return;
    int wend = min(wstart + WSPAN, span);
    int wn = wend - wstart;
    int tid = threadIdx.x;
    if (tid == 0) sh_before = 0;
    for (int i = tid; i < wn; i += 256) { lcnt_lo[i] = 0; lcnt_hi[i] = 0; }
    __syncthreads();
    int p0 = bbase[b], p1 = bbase[b + 1];
    int nbefore = 0;
    for (int i = p0 + tid; i < p1; i += 256) {
        int wd = epack[i];
        int ld = wd >> 17;
        if (ld < wstart) nbefore++;
        else if (ld < wend) {
            int r = ld - wstart;
            int s = wd & 0x1FFFF;
            if (s < NHALF) {
                int slot = atomicAdd(&lcnt_lo[r], 1);
                if (slot < KMAX) lcsr[r * LSTRIDE + slot] = s;
            } else {
                int slot = atomicAdd(&lcnt_hi[r], 1);
                if (slot < KMAX) lcsr[r * LSTRIDE + (KMAX - slot)] = s;
            }
        }
    }
    atomicAdd(&sh_before, nbefore);
    __syncthreads();
    // clamp counts (degree>96 never occurs statistically; keep graceful caps)
    for (int i = tid; i < wn; i += 256) {
        int cl = min(lcnt_lo[i], KMAX);
        int ch = min(lcnt_hi[i], KMAX);
        if (ch > LSTRIDE - cl) ch = LSTRIDE - cl;
        if (ch < 0) ch = 0;
        lcnt_lo[i] = cl;
        lcnt_hi[i] = ch;
    }
    __syncthreads();
    if (tid == 0) {
        int run = 0;
        for (int i = 0; i < wn; i++) { lbase[i] = run; run += lcnt_lo[i] + lcnt_hi[i]; }
        lbase[wn] = run;
    }
    __syncthreads();
    int w0 = p0 + sh_before;
    for (int i = tid; i < wn; i += 256) {
        off[base + wstart + i] = w0 + lbase[i];
        sp[base + wstart + i]  = w0 + lbase[i] + lcnt_lo[i];
    }
    if (base + wend == NN && tid == 0) off[NN] = w0 + lbase[wn];
    int m = lbase[wn];
    for (int j = tid; j < m; j += 256) {
        int lo = 0, hi = wn - 1;
        while (lo < hi) {
            int mid = (lo + hi + 1) >> 1;
            if (lbase[mid] <= j) lo = mid; else hi = mid - 1;
        }
        int l = j - lbase[lo];
        int cl = lcnt_lo[lo];
        int slot = (l < cl) ? l : (KMAX - (l - cl));
        srcs[w0 + j] = lcsr[lo * LSTRIDE + slot];
    }
}

__device__ __forceinline__ unsigned bf16rn(float f) {
    unsigned b = __float_as_uint(f);
    return (b + 0x7fffu + ((b >> 16) & 1u)) >> 16;   // RNE
}

__device__ __forceinline__ void acc_row(float* a, uint4 v) {
    a[0] += __uint_as_float(v.x << 16);
    a[1] += __uint_as_float(v.x & 0xffff0000u);
    a[2] += __uint_as_float(v.y << 16);
    a[3] += __uint_as_float(v.y & 0xffff0000u);
    a[4] += __uint_as_float(v.z << 16);
    a[5] += __uint_as_float(v.z & 0xffff0000u);
    a[6] += __uint_as_float(v.w << 16);
    a[7] += __uint_as_float(v.w & 0xffff0000u);
}

// ---- projection q(bf16) = BN(h) @ w1, 4-way K-split (round-0 form; q single table
// [N][4 x uint4] = 64B rows so gather loads full lines).
template <int FIN>
__global__ __launch_bounds__(256) void proj_kernel(const float* __restrict__ hin,
                                                   const float* __restrict__ w1,
                                                   const float* __restrict__ stats_prev,
                                                   const float* __restrict__ gamma,
                                                   const float* __restrict__ beta,
                                                   uint4* __restrict__ q4) {
    constexpr int JC = FIN / 4;           // K rows per wave: 32 (FIN=128) / 8 (FIN=32)
    __shared__ float sa[32], sc[32];
    __shared__ float part[4 * 64 * 33];   // [wv][node][ch], +1 pad -> 33792 B
    int tid = threadIdx.x;
    if constexpr (FIN == 32) {
        if (tid < 32) {
            float mean = stats_prev[tid] * (1.0f / NN);
            float var  = fmaxf(stats_prev[32 + tid] * (1.0f / NN) - mean * mean, 0.f);
            float av = gamma[tid] * rsqrtf(var + 1e-5f);
            sa[tid] = av;
            sc[tid] = beta[tid] - mean * av;
        }
        __syncthreads();
    }
    int wv = __builtin_amdgcn_readfirstlane(tid >> 6);   // K-part, wave-uniform
    int ln = tid & 63;                                   // node within block
    int n = blockIdx.x * 64 + ln;
    float acc[32];
#pragma unroll
    for (int c = 0; c < 32; c++) acc[c] = 0.f;
    if (n < NN) {
        const float4* h4 = (const float4*)(hin + (size_t)n * FIN + wv * JC);
        float hv[JC];
#pragma unroll
        for (int k = 0; k < JC / 4; k++) {
            float4 v = h4[k];
            hv[4*k] = v.x; hv[4*k+1] = v.y; hv[4*k+2] = v.z; hv[4*k+3] = v.w;
        }
        if constexpr (FIN == 32) {
#pragma unroll
            for (int j = 0; j < JC; j++) hv[j] = fmaf(hv[j], sa[wv * JC + j], sc[wv * JC + j]);
        }
#pragma unroll 4
        for (int j = 0; j < JC; j++) {
            float hvj = hv[j];
            const float* wrow = w1 + (size_t)(wv * JC + j) * 32;  // wave-uniform -> s_load
#pragma unroll
            for (int c = 0; c < 32; c++) acc[c] = fmaf(hvj, wrow[c], acc[c]);
        }
    }
    float* my = part + (wv * 64 + ln) * 33;
#pragma unroll
    for (int c = 0; c < 32; c++) my[c] = acc[c];
    __syncthreads();
    // reduce 4 partials; thread t -> node t>>2, channels (t&3)*8..+8; write bf16 q
    int node = tid >> 2, p = tid & 3;
    int n2 = blockIdx.x * 64 + node;
    if (n2 >= NN) return;
    float r[8];
#pragma unroll
    for (int k = 0; k < 8; k++) {
        int c = p * 8 + k;
        r[k] = (part[(0 * 64 + node) * 33 + c] + part[(1 * 64 + node) * 33 + c])
             + (part[(2 * 64 + node) * 33 + c] + part[(3 * 64 + node) * 33 + c]);
    }
    uint4 u;
    u.x = bf16rn(r[0]) | (bf16rn(r[1]) << 16);
    u.y = bf16rn(r[2]) | (bf16rn(r[3]) << 16);
    u.z = bf16rn(r[4]) | (bf16rn(r[5]) << 16);
    u.w = bf16rn(r[6]) | (bf16rn(r[7]) << 16);
    q4[(size_t)n2 * 4 + p] = u;
}

// ---- gather, node-split pass HS: accumulates edges whose src half == HS.
// Edge-parallel: 8 lanes/node, lane p owns edges i = e0+p, e0+p+8, ...; loads full
// 64B q row (4 dwordx4 from one line). Pass 0 touches q[0..NHALF) = 3.2 MB (L2-
// resident/XCD), pass 1 the upper half. Reduce-scatter via shfl_xor lands each
// lane's 4 output channels in fixed registers (no runtime-indexed arrays).
template <int HS>
__global__ __launch_bounds__(256) void gather_ns_kernel(const uint4* __restrict__ q4,
                                                        const int* __restrict__ srcs,
                                                        const int* __restrict__ off,
                                                        const int* __restrict__ sp,
                                                        const float* __restrict__ bias,
                                                        float* __restrict__ agg) {
    int t = blockIdx.x * 256 + threadIdx.x;
    int n = t >> 3;
    if (n >= NN) return;
    int p = t & 7;
    int e0, e1;
    if (HS == 0) { e0 = off[n]; e1 = sp[n]; }
    else         { e0 = sp[n];  e1 = off[n + 1]; }
    float acc[32];
#pragma unroll
    for (int c = 0; c < 32; c++) acc[c] = 0.f;
    int i = e0 + p;
    for (; i + 8 < e1; i += 16) {
        int s0 = __builtin_nontemporal_load(srcs + i);
        int s1 = __builtin_nontemporal_load(srcs + i + 8);
        uint4 a0 = q4[(size_t)s0 * 4 + 0];
        uint4 a1 = q4[(size_t)s0 * 4 + 1];
        uint4 a2 = q4[(size_t)s0 * 4 + 2];
        uint4 a3 = q4[(size_t)s0 * 4 + 3];
        uint4 c0 = q4[(size_t)s1 * 4 + 0];
        uint4 c1 = q4[(size_t)s1 * 4 + 1];
        uint4 c2 = q4[(size_t)s1 * 4 + 2];
        uint4 c3 = q4[(size_t)s1 * 4 + 3];
        acc_row(acc + 0,  a0); acc_row(acc + 8,  a1);
        acc_row(acc + 16, a2); acc_row(acc + 24, a3);
        acc_row(acc + 0,  c0); acc_row(acc + 8,  c1);
        acc_row(acc + 16, c2); acc_row(acc + 24, c3);
    }
    if (i < e1) {
        int s0 = __builtin_nontemporal_load(srcs + i);
        uint4 a0 = q4[(size_t)s0 * 4 + 0];
        uint4 a1 = q4[(size_t)s0 * 4 + 1];
        uint4 a2 = q4[(size_t)s0 * 4 + 2];
        uint4 a3 = q4[(size_t)s0 * 4 + 3];
        acc_row(acc + 0,  a0); acc_row(acc + 8,  a1);
        acc_row(acc + 16, a2); acc_row(acc + 24, a3);
    }
    // reduce-scatter across the node's 8 lanes; final 4 channels in k4[0..3]
    int sel1 = p & 1, sel2 = (p >> 1) & 1, sel3 = (p >> 2) & 1;
    float k16[16];
#pragma unroll
    for (int r = 0; r < 16; r++) {
        float send = sel1 ? acc[r] : acc[r + 16];
        float recv = __shfl_xor(send, 1);
        k16[r] = (sel1 ? acc[r + 16] : acc[r]) + recv;
    }
    float k8[8];
#pragma unroll
    for (int r = 0; r < 8; r++) {
        float send = sel2 ? k16[r] : k16[r + 8];
        float recv = __shfl_xor(send, 2);
        k8[r] = (sel2 ? k16[r + 8] : k16[r]) + recv;
    }
    float k4[4];
#pragma unroll
    for (int r = 0; r < 4; r++) {
        float send = sel3 ? k8[r] : k8[r + 4];
        float recv = __shfl_xor(send, 4);
        k4[r] = (sel3 ? k8[r + 4] : k8[r]) + recv;
    }
    int base = 16 * sel1 + 8 * sel2 + 4 * sel3;   // this lane's 4 channels
    // self term in the pass owning node n's half
    bool own_self = (HS == 0) ? (n < NHALF) : (n >= NHALF);
    if (own_self) {
        uint4 v = q4[(size_t)n * 4 + (base >> 3)];
        unsigned w0 = sel3 ? v.z : v.x;
        unsigned w1 = sel3 ? v.w : v.y;
        k4[0] += __uint_as_float(w0 << 16);
        k4[1] += __uint_as_float(w0 & 0xffff0000u);
        k4[2] += __uint_as_float(w1 << 16);
        k4[3] += __uint_as_float(w1 & 0xffff0000u);
    }
    f32x4* ar = (f32x4*)(agg + (size_t)n * 32 + base);
    f32x4 o;
    if (HS == 0) {
        const float4 bv = *(const float4*)(bias + base);
        o.x = k4[0] + bv.x; o.y = k4[1] + bv.y; o.z = k4[2] + bv.z; o.w = k4[3] + bv.w;
    } else {
        f32x4 g = __builtin_nontemporal_load(ar);
        o.x = k4[0] + g.x; o.y = k4[1] + g.y; o.z = k4[2] + g.z; o.w = k4[3] + g.w;
    }
    __builtin_nontemporal_store(o, ar);
}

// ---- MLP tail: h = relu(relu(agg)@w2 + b2); accumulate raw BN stats (layer slot).
__global__ __launch_bounds__(256) void mlp_kernel(const float* __restrict__ agg,
                                                  const float* __restrict__ w2,
                                                  const float* __restrict__ b2,
                                                  float* __restrict__ r,
                                                  float* __restrict__ stats) {
    __shared__ float tile[256 * 33];
    __shared__ float ps[8 * 32];
    __shared__ float pq[8 * 32];
    int tid = threadIdx.x;
    int n = blockIdx.x * 256 + tid;
    float rc[32];
    if (n < NN) {
        float u[32];
        const float4* a4 = (const float4*)(agg + (size_t)n * 32);
#pragma unroll
        for (int k = 0; k < 8; k++) {
            float4 v = a4[k];
            u[4*k]   = fmaxf(v.x, 0.f);
            u[4*k+1] = fmaxf(v.y, 0.f);
            u[4*k+2] = fmaxf(v.z, 0.f);
            u[4*k+3] = fmaxf(v.w, 0.f);
        }
#pragma unroll
        for (int c = 0; c < 32; c++) rc[c] = b2[c];
#pragma unroll 4
        for (int j = 0; j < 32; j++) {
            float uj = u[j];
            const float* wrow = w2 + (size_t)j * 32;
#pragma unroll
            for (int c = 0; c < 32; c++) rc[c] = fmaf(uj, wrow[c], rc[c]);
        }
#pragma unroll
        for (int c = 0; c < 32; c++) rc[c] = fmaxf(rc[c], 0.f);
        float4* rr = (float4*)(r + (size_t)n * 32);
#pragma unroll
        for (int k = 0; k < 8; k++) {
            float4 v; v.x = rc[4*k]; v.y = rc[4*k+1]; v.z = rc[4*k+2]; v.w = rc[4*k+3];
            rr[k] = v;
        }
    } else {
#pragma unroll
        for (int c = 0; c < 32; c++) rc[c] = 0.f;
    }
#pragma unroll
    for (int c = 0; c < 32; c++) tile[tid * 33 + c] = rc[c];
    __syncthreads();
    {
        int c = tid & 31, rb = tid >> 5;
        float s = 0.f, sq = 0.f;
        for (int it = 0; it < 32; it++) {
            float v = tile[(rb * 32 + it) * 33 + c];
            s += v; sq += v * v;
        }
        ps[rb * 32 + c] = s; pq[rb * 32 + c] = sq;
    }
    __syncthreads();
    if (tid < 32) {
        float s = 0.f, sq = 0.f;
#pragma unroll
        for (int rb = 0; rb < 8; rb++) { s += ps[rb * 32 + tid]; sq += pq[rb * 32 + tid]; }
        atomicAdd(&stats[tid], s);
        atomicAdd(&stats[32 + tid], sq);
    }
}

// ---- pooling: segment sums of raw h3 (sorted batch -> run-length flush)
#define PR 16
__global__ __launch_bounds__(256) void pool_kernel(const float* __restrict__ h,
                                                   const int* __restrict__ batch,
                                                   float* __restrict__ pooled,
                                                   float* __restrict__ pcnt) {
    int t = blockIdx.x * 256 + threadIdx.x;
    int c = t & 31;
    int g = t >> 5;
    int r0 = g * PR;
    if (r0 >= NN) return;
    int r1 = min(r0 + PR, NN);
    int cur = batch[r0];
    float acc = 0.f, cn = 0.f;
    for (int rr = r0; rr < r1; rr++) {
        int b = batch[rr];
        if (b != cur) {
            atomicAdd(&pooled[cur * 32 + c], acc);
            if (c == 0) atomicAdd(&pcnt[cur], cn);
            acc = 0.f; cn = 0.f; cur = b;
        }
        acc += h[(size_t)rr * 32 + c];
        cn += 1.f;
    }
    atomicAdd(&pooled[cur * 32 + c], acc);
    if (c == 0) atomicAdd(&pcnt[cur], cn);
}

// ---- head: BN3 (from raw stats3) on pooled means, fc1+relu, fc2, log_softmax
__global__ __launch_bounds__(128) void head_kernel(const float* __restrict__ pooled,
                                                   const float* __restrict__ pcnt,
                                                   const float* __restrict__ stats3,
                                                   const float* __restrict__ g3,
                                                   const float* __restrict__ be3,
                                                   const float* __restrict__ fc1w,
                                                   const float* __restrict__ fc1b,
                                                   const float* __restrict__ fc2w,
                                                   const float* __restrict__ fc2b,
                                                   float* __restrict__ out) {
    __shared__ float sa[32], sc[32];
    int g = threadIdx.x;
    if (g < 32) {
        float mean = stats3[g] * (1.0f / NN);
        float var  = fmaxf(stats3[32 + g] * (1.0f / NN) - mean * mean, 0.f);
        float av = g3[g] * rsqrtf(var + 1e-5f);
        sa[g] = av;
        sc[g] = be3[g] - mean * av;
    }
    __syncthreads();
    if (g >= BB) return;
    float inv = 1.f / fmaxf(pcnt[g], 1.f);
    float xv[32];
#pragma unroll
    for (int c = 0; c < 32; c++) xv[c] = fmaf(sa[c], pooled[g * 32 + c] * inv, sc[c]);
    float u[32];
#pragma unroll 4
    for (int k = 0; k < 32; k++) {
        float s = fc1b[k];
#pragma unroll
        for (int c = 0; c < 32; c++) s = fmaf(xv[c], fc1w[c * 32 + k], s);
        u[k] = fmaxf(s, 0.f);
    }
    float l[8];
#pragma unroll
    for (int o = 0; o < 8; o++) {
        float s = fc2b[o];
#pragma unroll
        for (int k = 0; k < 32; k++) s = fmaf(u[k], fc2w[k * 8 + o], s);
        l[o] = s;
    }
    float m = l[0];
#pragma unroll
    for (int o = 1; o < 8; o++) m = fmaxf(m, l[o]);
    float se = 0.f;
#pragma unroll
    for (int o = 0; o < 8; o++) se += expf(l[o] - m);
    float lse = logf(se) + m;
#pragma unroll
    for (int o = 0; o < 8; o++) out[g * 8 + o] = l[o] - lse;
}

extern "C" void kernel_launch(void* const* d_in, const int* in_sizes, int n_in,
                              void* d_out, int out_size, void* d_ws, size_t ws_size,
                              hipStream_t stream) {
    const float* x    = (const float*)d_in[0];
    const int*   ei   = (const int*)d_in[1];
    const int*   batch= (const int*)d_in[2];
    const float* w1_0 = (const float*)d_in[3];
    const float* b1_0 = (const float*)d_in[4];
    const float* w2_0 = (const float*)d_in[5];
    const float* b2_0 = (const float*)d_in[6];
    const float* g_0  = (const float*)d_in[7];
    const float* be_0 = (const float*)d_in[8];
    const float* w1s  = (const float*)d_in[9];
    const float* b1s  = (const float*)d_in[10];
    const float* w2s  = (const float*)d_in[11];
    const float* b2s  = (const float*)d_in[12];
    const float* gs   = (const float*)d_in[13];
    const float* bes  = (const float*)d_in[14];
    const float* fc1w = (const float*)d_in[15];
    const float* fc1b = (const float*)d_in[16];
    const float* fc2w = (const float*)d_in[17];
    const float* fc2b = (const float*)d_in[18];
    float* out = (float*)d_out;

    char* ws = (char*)d_ws;
    uint4*    q4     = (uint4*)(ws + Q_OFF);        // [N][4] uint4 (64B rows)
    float*    agg    = (float*)(ws + AGG_OFF);      // [N][32] f32
    float*    h      = (float*)(ws + H_OFF);
    int*      epack  = (int*)(ws + EPACK_OFF);
    int*      srcs   = (int*)(ws + SRC_OFF);
    int*      off    = (int*)(ws + OFF_OFF);
    int*      hist   = (int*)(ws + HIST_OFF);
    int*      start  = (int*)(ws + START_OFF);
    int*      bbase  = (int*)(ws + BBASE_OFF);
    float*    stats  = (float*)(ws + STATS_OFF);   // 4 slots x 64
    float*    pooled = (float*)(ws + POOLED_OFF);
    float*    pcnt   = (float*)(ws + PCNT_OFF);
    int*      sp     = (int*)(ws + SP_OFF);

    (void)hipMemsetAsync(ws + ZERO_OFF, 0, ZERO_BYTES, stream);

    // CSR build chain
    hist_kernel<<<EBLK, 256, 0, stream>>>(ei, hist);
    bucket_scan_kernel<<<1, NBKT, 0, stream>>>(hist, bbase, start);
    scatter_kernel<<<EBLK, 256, 0, stream>>>(ei, start, epack);
    csr_compact_kernel<<<NBKT * 4, 256, 0, stream>>>(epack, bbase, off, sp, srcs);

    const int pblk = (NN + 63) / 64;
    const int nblk = (NN + 255) / 256;
    const int gblk = (NN * 8 + 255) / 256;   // 3125 exactly

    // layer 0 (F_IN=128, no input BN)
    proj_kernel<128><<<pblk, 256, 0, stream>>>(x, w1_0, nullptr, nullptr, nullptr, q4);
    gather_ns_kernel<0><<<gblk, 256, 0, stream>>>(q4, srcs, off, sp, b1_0, agg);
    gather_ns_kernel<1><<<gblk, 256, 0, stream>>>(q4, srcs, off, sp, b1_0, agg);
    mlp_kernel<<<nblk, 256, 0, stream>>>(agg, w2_0, b2_0, h, stats);

    // layers 1..3, prev BN computed in proj from raw stats slot
    for (int i = 0; i < 3; i++) {
        const float* st_prev = stats + i * 64;
        proj_kernel<32><<<pblk, 256, 0, stream>>>(h, w1s + i * 1024, st_prev,
                                                  gs + i * 32, bes + i * 32, q4);
        gather_ns_kernel<0><<<gblk, 256, 0, stream>>>(q4, srcs, off, sp, b1s + i * 32, agg);
        gather_ns_kernel<1><<<gblk, 256, 0, stream>>>(q4, srcs, off, sp, b1s + i * 32, agg);
        mlp_kernel<<<nblk, 256, 0, stream>>>(agg, w2s + i * 1024, b2s + i * 32, h,
                                             stats + (i + 1) * 64);
    }

    int pthreads = ((NN + PR - 1) / PR) * 32;
    pool_kernel<<<(pthreads + 255) / 256, 256, 0, stream>>>(h, batch, pooled, pcnt);
    head_kernel<<<1, 128, 0, stream>>>(pooled, pcnt, stats + 3 * 64, gs + 2 * 32,
                                       bes + 2 * 32, fc1w, fc1b, fc2w, fc2b, out);
}

// Round 4
// 577.194 us; speedup vs baseline: 1.2197x; 1.0560x over previous
//
#include <hip/hip_runtime.h>
#include <hip/hip_bf16.h>

#define NN   100000
#define EE   3200000
#define HH   32
#define BB   128
#define KMAX 96
#define LSTRIDE 97       // LDS row stride (97 odd -> conflict-free-ish)
#define NBKT 1024        // fine dst buckets (one per csr block)
#define BSPAN 98         // ceil(NN/NBKT)
#define EBLK 256         // edge-chunk blocks
#define CHUNK 12500      // EE / EBLK exactly

typedef float f32x4 __attribute__((ext_vector_type(4)));

// ws layout (bytes), non-overlapping (~47.7 MB)
static constexpr size_t Q_OFF      = 0;           // N*64B bf16 rows = 6.4 MB
static constexpr size_t EPACK_OFF  = 6400000;     // EE int = 12.8 MB
static constexpr size_t H_OFF      = 19200000;    // N*32 f32 = 12.8 MB
static constexpr size_t SRC_OFF    = 32000000;    // EE int dense csr
static constexpr size_t OFF_OFF    = 44800000;    // (N+1) int
static constexpr size_t HIST_OFF   = 45300000;    // EBLK*NBKT int = 1 MB
static constexpr size_t CUR_OFF    = 46400000;    // NBKT int cursors
static constexpr size_t BBASE_OFF  = 47500000;    // (NBKT+1) int
static constexpr size_t STATS_OFF  = 47600000;    // 4 layers x 64 f32
static constexpr size_t POOLED_OFF = 47601024;    // B*32 f32
static constexpr size_t PCNT_OFF   = 47617408;    // B f32
static constexpr size_t ZERO_OFF   = STATS_OFF;
static constexpr size_t ZERO_BYTES = 17920;

// ---- K1: per-block LDS histogram of dst buckets (1024 fine buckets)
__global__ __launch_bounds__(256) void hist_kernel(const int* __restrict__ ei,
                                                   int* __restrict__ hist) {
    __shared__ int lh[NBKT];
    int tid = threadIdx.x, blk = blockIdx.x;
    for (int i = tid; i < NBKT; i += 256) lh[i] = 0;
    __syncthreads();
    int e0 = blk * CHUNK;
    for (int e = e0 + tid; e < e0 + CHUNK; e += 256) {
        int d = ei[EE + e];
        atomicAdd(&lh[d / BSPAN], 1);
    }
    __syncthreads();
    for (int i = tid; i < NBKT; i += 256) hist[blk * NBKT + i] = lh[i];
}

// ---- K2: bucket totals + 1024-wide scan -> bbase, cursor (no serial 256-loop)
__global__ __launch_bounds__(1024) void bucket_scan_kernel(const int* __restrict__ hist,
                                                           int* __restrict__ bbase,
                                                           int* __restrict__ cursor) {
    __shared__ int sm[NBKT];
    int t = threadIdx.x;
    int mine = 0;
    for (int blk = 0; blk < EBLK; blk++) mine += hist[blk * NBKT + t];
    sm[t] = mine;
    __syncthreads();
    for (int off = 1; off < NBKT; off <<= 1) {
        int v = (t >= off) ? sm[t - off] : 0;
        __syncthreads();
        sm[t] += v;
        __syncthreads();
    }
    int base = sm[t] - mine;   // exclusive
    bbase[t] = base;
    cursor[t] = base;
    if (t == NBKT - 1) bbase[NBKT] = sm[t];
}

// ---- K3: scatter packed (src | dstoff<<17); block allocates bucket space via
// one global atomicAdd per (block,bucket) using the hist counts.
__global__ __launch_bounds__(256) void scatter_kernel(const int* __restrict__ ei,
                                                      const int* __restrict__ hist,
                                                      int* __restrict__ cursor,
                                                      int* __restrict__ epack) {
    __shared__ int lbs[NBKT];
    __shared__ int lh[NBKT];
    int tid = threadIdx.x, blk = blockIdx.x;
    for (int i = tid; i < NBKT; i += 256) {
        int c = hist[blk * NBKT + i];
        lbs[i] = (c > 0) ? atomicAdd(&cursor[i], c) : 0;
        lh[i] = 0;
    }
    __syncthreads();
    int e0 = blk * CHUNK;
    for (int e = e0 + tid; e < e0 + CHUNK; e += 256) {
        int s = ei[e];
        int d = ei[EE + e];
        int b = d / BSPAN;
        int slot = lbs[b] + atomicAdd(&lh[b], 1);
        epack[slot] = s | ((d - b * BSPAN) << 17);
    }
}

// ---- K4: compact CSR build — one bucket per block, single scan of its epack slice
__global__ __launch_bounds__(256) void csr_compact_kernel(const int* __restrict__ epack,
                                                          const int* __restrict__ bbase,
                                                          int* __restrict__ off,
                                                          int* __restrict__ srcs) {
    __shared__ int lcnt[BSPAN];
    __shared__ int lbase[BSPAN + 1];
    __shared__ int lcsr[BSPAN * LSTRIDE];   // 98*97*4 = 38024 B
    int b = blockIdx.x;
    int base = b * BSPAN;
    int span = NN - base;
    if (span <= 0) return;                  // buckets past NN have no edges
    if (span > BSPAN) span = BSPAN;
    int tid = threadIdx.x;
    for (int i = tid; i < span; i += 256) lcnt[i] = 0;
    __syncthreads();
    int p0 = bbase[b], p1 = bbase[b + 1];
    for (int i = p0 + tid; i < p1; i += 256) {
        int wd = epack[i];
        int ld = wd >> 17;
        int slot = atomicAdd(&lcnt[ld], 1);
        if (slot < KMAX) lcsr[ld * LSTRIDE + slot] = wd & 0x1FFFF;
    }
    __syncthreads();
    if (tid == 0) {
        int run = 0;
        for (int i = 0; i < span; i++) { lbase[i] = run; run += min(lcnt[i], KMAX); }
        lbase[span] = run;
    }
    __syncthreads();
    for (int i = tid; i < span; i += 256) off[base + i] = p0 + lbase[i];
    if (base + span == NN && tid == 0) off[NN] = p0 + lbase[span];
    int m = lbase[span];
    for (int j = tid; j < m; j += 256) {
        int lo = 0, hi = span - 1;
        while (lo < hi) {
            int mid = (lo + hi + 1) >> 1;
            if (lbase[mid] <= j) lo = mid; else hi = mid - 1;
        }
        srcs[p0 + j] = lcsr[lo * LSTRIDE + (j - lbase[lo])];
    }
}

__device__ __forceinline__ unsigned bf16rn(float f) {
    unsigned b = __float_as_uint(f);
    return (b + 0x7fffu + ((b >> 16) & 1u)) >> 16;   // RNE
}

__device__ __forceinline__ void acc_row(float* a, uint4 v) {
    a[0] += __uint_as_float(v.x << 16);
    a[1] += __uint_as_float(v.x & 0xffff0000u);
    a[2] += __uint_as_float(v.y << 16);
    a[3] += __uint_as_float(v.y & 0xffff0000u);
    a[4] += __uint_as_float(v.z << 16);
    a[5] += __uint_as_float(v.z & 0xffff0000u);
    a[6] += __uint_as_float(v.w << 16);
    a[7] += __uint_as_float(v.w & 0xffff0000u);
}

// ---- projection q(bf16) = BN(h) @ w1, 4-way K-split; q rows = 64B.
template <int FIN>
__global__ __launch_bounds__(256) void proj_kernel(const float* __restrict__ hin,
                                                   const float* __restrict__ w1,
                                                   const float* __restrict__ stats_prev,
                                                   const float* __restrict__ gamma,
                                                   const float* __restrict__ beta,
                                                   uint4* __restrict__ q4) {
    constexpr int JC = FIN / 4;           // K rows per wave: 32 (FIN=128) / 8 (FIN=32)
    __shared__ float sa[32], sc[32];
    __shared__ float part[4 * 64 * 33];   // [wv][node][ch], +1 pad -> 33792 B
    int tid = threadIdx.x;
    if constexpr (FIN == 32) {
        if (tid < 32) {
            float mean = stats_prev[tid] * (1.0f / NN);
            float var  = fmaxf(stats_prev[32 + tid] * (1.0f / NN) - mean * mean, 0.f);
            float av = gamma[tid] * rsqrtf(var + 1e-5f);
            sa[tid] = av;
            sc[tid] = beta[tid] - mean * av;
        }
        __syncthreads();
    }
    int wv = __builtin_amdgcn_readfirstlane(tid >> 6);   // K-part, wave-uniform
    int ln = tid & 63;                                   // node within block
    int n = blockIdx.x * 64 + ln;
    float acc[32];
#pragma unroll
    for (int c = 0; c < 32; c++) acc[c] = 0.f;
    if (n < NN) {
        const float4* h4 = (const float4*)(hin + (size_t)n * FIN + wv * JC);
        float hv[JC];
#pragma unroll
        for (int k = 0; k < JC / 4; k++) {
            float4 v = h4[k];
            hv[4*k] = v.x; hv[4*k+1] = v.y; hv[4*k+2] = v.z; hv[4*k+3] = v.w;
        }
        if constexpr (FIN == 32) {
#pragma unroll
            for (int j = 0; j < JC; j++) hv[j] = fmaf(hv[j], sa[wv * JC + j], sc[wv * JC + j]);
        }
#pragma unroll 4
        for (int j = 0; j < JC; j++) {
            float hvj = hv[j];
            const float* wrow = w1 + (size_t)(wv * JC + j) * 32;  // wave-uniform -> s_load
#pragma unroll
            for (int c = 0; c < 32; c++) acc[c] = fmaf(hvj, wrow[c], acc[c]);
        }
    }
    float* my = part + (wv * 64 + ln) * 33;
#pragma unroll
    for (int c = 0; c < 32; c++) my[c] = acc[c];
    __syncthreads();
    int node = tid >> 2, p = tid & 3;
    int n2 = blockIdx.x * 64 + node;
    if (n2 >= NN) return;
    float r[8];
#pragma unroll
    for (int k = 0; k < 8; k++) {
        int c = p * 8 + k;
        r[k] = (part[(0 * 64 + node) * 33 + c] + part[(1 * 64 + node) * 33 + c])
             + (part[(2 * 64 + node) * 33 + c] + part[(3 * 64 + node) * 33 + c]);
    }
    uint4 u;
    u.x = bf16rn(r[0]) | (bf16rn(r[1]) << 16);
    u.y = bf16rn(r[2]) | (bf16rn(r[3]) << 16);
    u.z = bf16rn(r[4]) | (bf16rn(r[5]) << 16);
    u.w = bf16rn(r[6]) | (bf16rn(r[7]) << 16);
    q4[(size_t)n2 * 4 + p] = u;
}

// ---- fused gather + MLP tail: z = q[n] + b1 + sum q[src]; u = relu(z);
// h = relu(u@w2 + b2); accumulate raw BN stats. 8 lanes/node, edge-parallel,
// shfl reduce-scatter -> 4 fixed-register channels/lane; 32 nodes/block via LDS.
__global__ __launch_bounds__(256) void gather_mlp_kernel(const uint4* __restrict__ q4,
                                                         const int* __restrict__ srcs,
                                                         const int* __restrict__ off,
                                                         const float* __restrict__ b1,
                                                         const float* __restrict__ w2,
                                                         const float* __restrict__ b2,
                                                         float* __restrict__ hout,
                                                         float* __restrict__ stats) {
    __shared__ float w2t[32 * 33];
    __shared__ float ut[32 * 33];     // 32 nodes x 32 ch (+pad)
    __shared__ float pst[32 * 8];     // 4 waves x 8 lanes x (4 s + 4 sq)
    int tid = threadIdx.x;
    for (int i = tid; i < 1024; i += 256) w2t[(i >> 5) * 33 + (i & 31)] = w2[i];
    int t = blockIdx.x * 256 + tid;
    int n = t >> 3;                   // grid exact: always < NN
    int p = tid & 7;
    int nl = (tid >> 3) & 31;
    int e0 = off[n], e1 = off[n + 1];
    float acc[32];
#pragma unroll
    for (int c = 0; c < 32; c++) acc[c] = 0.f;
    int i = e0 + p;
    for (; i + 8 < e1; i += 16) {
        int s0 = __builtin_nontemporal_load(srcs + i);
        int s1 = __builtin_nontemporal_load(srcs + i + 8);
        uint4 a0 = q4[(size_t)s0 * 4 + 0];
        uint4 a1 = q4[(size_t)s0 * 4 + 1];
        uint4 a2 = q4[(size_t)s0 * 4 + 2];
        uint4 a3 = q4[(size_t)s0 * 4 + 3];
        uint4 c0 = q4[(size_t)s1 * 4 + 0];
        uint4 c1 = q4[(size_t)s1 * 4 + 1];
        uint4 c2 = q4[(size_t)s1 * 4 + 2];
        uint4 c3 = q4[(size_t)s1 * 4 + 3];
        acc_row(acc + 0,  a0); acc_row(acc + 8,  a1);
        acc_row(acc + 16, a2); acc_row(acc + 24, a3);
        acc_row(acc + 0,  c0); acc_row(acc + 8,  c1);
        acc_row(acc + 16, c2); acc_row(acc + 24, c3);
    }
    if (i < e1) {
        int s0 = __builtin_nontemporal_load(srcs + i);
        uint4 a0 = q4[(size_t)s0 * 4 + 0];
        uint4 a1 = q4[(size_t)s0 * 4 + 1];
        uint4 a2 = q4[(size_t)s0 * 4 + 2];
        uint4 a3 = q4[(size_t)s0 * 4 + 3];
        acc_row(acc + 0,  a0); acc_row(acc + 8,  a1);
        acc_row(acc + 16, a2); acc_row(acc + 24, a3);
    }
    // reduce-scatter across the node's 8 lanes
    int sel1 = p & 1, sel2 = (p >> 1) & 1, sel3 = (p >> 2) & 1;
    float k16[16];
#pragma unroll
    for (int r = 0; r < 16; r++) {
        float send = sel1 ? acc[r] : acc[r + 16];
        float recv = __shfl_xor(send, 1);
        k16[r] = (sel1 ? acc[r + 16] : acc[r]) + recv;
    }
    float k8[8];
#pragma unroll
    for (int r = 0; r < 8; r++) {
        float send = sel2 ? k16[r] : k16[r + 8];
        float recv = __shfl_xor(send, 2);
        k8[r] = (sel2 ? k16[r + 8] : k16[r]) + recv;
    }
    float k4[4];
#pragma unroll
    for (int r = 0; r < 4; r++) {
        float send = sel3 ? k8[r] : k8[r + 4];
        float recv = __shfl_xor(send, 4);
        k4[r] = (sel3 ? k8[r + 4] : k8[r]) + recv;
    }
    int base = 16 * sel1 + 8 * sel2 + 4 * sel3;   // this lane's 4 channels
    // self term
    {
        uint4 v = q4[(size_t)n * 4 + (base >> 3)];
        unsigned w0 = sel3 ? v.z : v.x;
        unsigned w1 = sel3 ? v.w : v.y;
        k4[0] += __uint_as_float(w0 << 16);
        k4[1] += __uint_as_float(w0 & 0xffff0000u);
        k4[2] += __uint_as_float(w1 << 16);
        k4[3] += __uint_as_float(w1 & 0xffff0000u);
    }
    const float4 bv = *(const float4*)(b1 + base);
    float u0 = fmaxf(k4[0] + bv.x, 0.f);
    float u1 = fmaxf(k4[1] + bv.y, 0.f);
    float u2 = fmaxf(k4[2] + bv.z, 0.f);
    float u3 = fmaxf(k4[3] + bv.w, 0.f);
    float* urow = ut + nl * 33 + base;
    urow[0] = u0; urow[1] = u1; urow[2] = u2; urow[3] = u3;
    __syncthreads();
    // 32x32 matmul: this lane computes channels base..base+3
    const float4 b2v = *(const float4*)(b2 + base);
    float o0 = b2v.x, o1 = b2v.y, o2 = b2v.z, o3 = b2v.w;
    const float* un = ut + nl * 33;
#pragma unroll 8
    for (int j = 0; j < 32; j++) {
        float uj = un[j];
        const float* wr = w2t + j * 33 + base;
        o0 = fmaf(uj, wr[0], o0);
        o1 = fmaf(uj, wr[1], o1);
        o2 = fmaf(uj, wr[2], o2);
        o3 = fmaf(uj, wr[3], o3);
    }
    o0 = fmaxf(o0, 0.f); o1 = fmaxf(o1, 0.f);
    o2 = fmaxf(o2, 0.f); o3 = fmaxf(o3, 0.f);
    f32x4 hv; hv.x = o0; hv.y = o1; hv.z = o2; hv.w = o3;
    __builtin_nontemporal_store(hv, (f32x4*)(hout + (size_t)n * 32 + base));
    // BN stats: reduce over the wave's 8 nodes (lanes stride 8), then block, then atomic
    float s0 = o0, s1 = o1, s2 = o2, s3 = o3;
    float q0 = o0 * o0, q1 = o1 * o1, q2 = o2 * o2, q3 = o3 * o3;
#pragma unroll
    for (int m = 8; m < 64; m <<= 1) {
        s0 += __shfl_xor(s0, m); s1 += __shfl_xor(s1, m);
        s2 += __shfl_xor(s2, m); s3 += __shfl_xor(s3, m);
        q0 += __shfl_xor(q0, m); q1 += __shfl_xor(q1, m);
        q2 += __shfl_xor(q2, m); q3 += __shfl_xor(q3, m);
    }
    int wv = tid >> 6;
    if ((tid & 63) < 8) {
        float* ps = pst + (wv * 8 + p) * 8;
        ps[0] = s0; ps[1] = s1; ps[2] = s2; ps[3] = s3;
        ps[4] = q0; ps[5] = q1; ps[6] = q2; ps[7] = q3;
    }
    __syncthreads();
    if (tid < 64) {
        int c = tid & 31;
        int issq = tid >> 5;
        int psel = ((c >> 4) & 1) | (((c >> 3) & 1) << 1) | (((c >> 2) & 1) << 2);
        int k = c & 3;
        float s = 0.f;
#pragma unroll
        for (int w = 0; w < 4; w++) s += pst[(w * 8 + psel) * 8 + issq * 4 + k];
        atomicAdd(&stats[issq * 32 + c], s);
    }
}

// ---- pooling: segment sums of raw h3 (sorted batch -> run-length flush)
#define PR 16
__global__ __launch_bounds__(256) void pool_kernel(const float* __restrict__ h,
                                                   const int* __restrict__ batch,
                                                   float* __restrict__ pooled,
                                                   float* __restrict__ pcnt) {
    int t = blockIdx.x * 256 + threadIdx.x;
    int c = t & 31;
    int g = t >> 5;
    int r0 = g * PR;
    if (r0 >= NN) return;
    int r1 = min(r0 + PR, NN);
    int cur = batch[r0];
    float acc = 0.f, cn = 0.f;
    for (int rr = r0; rr < r1; rr++) {
        int b = batch[rr];
        if (b != cur) {
            atomicAdd(&pooled[cur * 32 + c], acc);
            if (c == 0) atomicAdd(&pcnt[cur], cn);
            acc = 0.f; cn = 0.f; cur = b;
        }
        acc += h[(size_t)rr * 32 + c];
        cn += 1.f;
    }
    atomicAdd(&pooled[cur * 32 + c], acc);
    if (c == 0) atomicAdd(&pcnt[cur], cn);
}

// ---- head: BN3 (from raw stats3) on pooled means, fc1+relu, fc2, log_softmax
__global__ __launch_bounds__(128) void head_kernel(const float* __restrict__ pooled,
                                                   const float* __restrict__ pcnt,
                                                   const float* __restrict__ stats3,
                                                   const float* __restrict__ g3,
                                                   const float* __restrict__ be3,
                                                   const float* __restrict__ fc1w,
                                                   const float* __restrict__ fc1b,
                                                   const float* __restrict__ fc2w,
                                                   const float* __restrict__ fc2b,
                                                   float* __restrict__ out) {
    __shared__ float sa[32], sc[32];
    int g = threadIdx.x;
    if (g < 32) {
        float mean = stats3[g] * (1.0f / NN);
        float var  = fmaxf(stats3[32 + g] * (1.0f / NN) - mean * mean, 0.f);
        float av = g3[g] * rsqrtf(var + 1e-5f);
        sa[g] = av;
        sc[g] = be3[g] - mean * av;
    }
    __syncthreads();
    if (g >= BB) return;
    float inv = 1.f / fmaxf(pcnt[g], 1.f);
    float xv[32];
#pragma unroll
    for (int c = 0; c < 32; c++) xv[c] = fmaf(sa[c], pooled[g * 32 + c] * inv, sc[c]);
    float u[32];
#pragma unroll 4
    for (int k = 0; k < 32; k++) {
        float s = fc1b[k];
#pragma unroll
        for (int c = 0; c < 32; c++) s = fmaf(xv[c], fc1w[c * 32 + k], s);
        u[k] = fmaxf(s, 0.f);
    }
    float l[8];
#pragma unroll
    for (int o = 0; o < 8; o++) {
        float s = fc2b[o];
#pragma unroll
        for (int k = 0; k < 32; k++) s = fmaf(u[k], fc2w[k * 8 + o], s);
        l[o] = s;
    }
    float m = l[0];
#pragma unroll
    for (int o = 1; o < 8; o++) m = fmaxf(m, l[o]);
    float se = 0.f;
#pragma unroll
    for (int o = 0; o < 8; o++) se += expf(l[o] - m);
    float lse = logf(se) + m;
#pragma unroll
    for (int o = 0; o < 8; o++) out[g * 8 + o] = l[o] - lse;
}

extern "C" void kernel_launch(void* const* d_in, const int* in_sizes, int n_in,
                              void* d_out, int out_size, void* d_ws, size_t ws_size,
                              hipStream_t stream) {
    const float* x    = (const float*)d_in[0];
    const int*   ei   = (const int*)d_in[1];
    const int*   batch= (const int*)d_in[2];
    const float* w1_0 = (const float*)d_in[3];
    const float* b1_0 = (const float*)d_in[4];
    const float* w2_0 = (const float*)d_in[5];
    const float* b2_0 = (const float*)d_in[6];
    const float* g_0  = (const float*)d_in[7];
    const float* be_0 = (const float*)d_in[8];
    const float* w1s  = (const float*)d_in[9];
    const float* b1s  = (const float*)d_in[10];
    const float* w2s  = (const float*)d_in[11];
    const float* b2s  = (const float*)d_in[12];
    const float* gs   = (const float*)d_in[13];
    const float* bes  = (const float*)d_in[14];
    const float* fc1w = (const float*)d_in[15];
    const float* fc1b = (const float*)d_in[16];
    const float* fc2w = (const float*)d_in[17];
    const float* fc2b = (const float*)d_in[18];
    float* out = (float*)d_out;

    char* ws = (char*)d_ws;
    uint4*    q4     = (uint4*)(ws + Q_OFF);        // [N][4] uint4 (64B rows)
    int*      epack  = (int*)(ws + EPACK_OFF);
    float*    h      = (float*)(ws + H_OFF);
    int*      srcs   = (int*)(ws + SRC_OFF);
    int*      off    = (int*)(ws + OFF_OFF);
    int*      hist   = (int*)(ws + HIST_OFF);
    int*      cursor = (int*)(ws + CUR_OFF);
    int*      bbase  = (int*)(ws + BBASE_OFF);
    float*    stats  = (float*)(ws + STATS_OFF);   // 4 slots x 64
    float*    pooled = (float*)(ws + POOLED_OFF);
    float*    pcnt   = (float*)(ws + PCNT_OFF);

    (void)hipMemsetAsync(ws + ZERO_OFF, 0, ZERO_BYTES, stream);

    // CSR build chain
    hist_kernel<<<EBLK, 256, 0, stream>>>(ei, hist);
    bucket_scan_kernel<<<1, NBKT, 0, stream>>>(hist, bbase, cursor);
    scatter_kernel<<<EBLK, 256, 0, stream>>>(ei, hist, cursor, epack);
    csr_compact_kernel<<<NBKT, 256, 0, stream>>>(epack, bbase, off, srcs);

    const int pblk = (NN + 63) / 64;
    const int gblk = (NN * 8) / 256;   // 3125 exactly

    // layer 0 (F_IN=128, no input BN)
    proj_kernel<128><<<pblk, 256, 0, stream>>>(x, w1_0, nullptr, nullptr, nullptr, q4);
    gather_mlp_kernel<<<gblk, 256, 0, stream>>>(q4, srcs, off, b1_0, w2_0, b2_0, h, stats);

    // layers 1..3, prev BN computed in proj from raw stats slot
    for (int i = 0; i < 3; i++) {
        const float* st_prev = stats + i * 64;
        proj_kernel<32><<<pblk, 256, 0, stream>>>(h, w1s + i * 1024, st_prev,
                                                  gs + i * 32, bes + i * 32, q4);
        gather_mlp_kernel<<<gblk, 256, 0, stream>>>(q4, srcs, off, b1s + i * 32,
                                                    w2s + i * 1024, b2s + i * 32, h,
                                                    stats + (i + 1) * 64);
    }

    int pthreads = ((NN + PR - 1) / PR) * 32;
    pool_kernel<<<(pthreads + 255) / 256, 256, 0, stream>>>(h, batch, pooled, pcnt);
    head_kernel<<<1, 128, 0, stream>>>(pooled, pcnt, stats + 3 * 64, gs + 2 * 32,
                                       bes + 2 * 32, fc1w, fc1b, fc2w, fc2b, out);
}